// Round 4
// baseline (771.777 us; speedup 1.0000x reference)
//
#include <hip/hip_runtime.h>
#include <stdint.h>

#define D_MODEL  1024
#define D_HIDDEN 4096
#define NE       8
#define T_TOK    8192
#define BM       256
#define BN       256
#define MAXT     72
#define ROWS_CAP 18432

typedef __attribute__((ext_vector_type(8))) short short8;
typedef __attribute__((ext_vector_type(4))) float f32x4;

__device__ inline uint16_t f2bf(float f) {
  uint32_t u = __float_as_uint(f);
  uint32_t r = (u + 0x7fffu + ((u >> 16) & 1u)) >> 16;
  return (uint16_t)r;
}

#define GLOAD16(gp, lp) __builtin_amdgcn_global_load_lds( \
  (const __attribute__((address_space(1))) uint32_t*)(gp), \
  (__attribute__((address_space(3))) uint32_t*)(lp), 16, 0, 0)

// ---------------- transpose + f32->bf16 convert: in [R][C] -> out [C][R] ----
// 64x64 tile, 256 threads; coalesced f32x4 reads, coalesced 16B bf16 writes.
__global__ void transpose_cvt(const float* __restrict__ in, uint16_t* __restrict__ out,
                              int R, int C) {
  __shared__ float tile[64][65];
  size_t eoff = (size_t)blockIdx.z * R * C;
  int c0 = blockIdx.x * 64, r0 = blockIdx.y * 64;
  int t = threadIdx.x;
  int lr = t >> 4, lc4 = (t & 15) * 4;
#pragma unroll
  for (int i = 0; i < 4; ++i) {
    int rr = i * 16 + lr;
    float4 v = *(const float4*)(in + eoff + (size_t)(r0 + rr) * C + c0 + lc4);
    tile[rr][lc4] = v.x; tile[rr][lc4 + 1] = v.y;
    tile[rr][lc4 + 2] = v.z; tile[rr][lc4 + 3] = v.w;
  }
  __syncthreads();
  int oc = t >> 3, orr = (t & 7) * 8;
#pragma unroll
  for (int i = 0; i < 2; ++i) {
    int cc = i * 32 + oc;
    short8 o;
#pragma unroll
    for (int j = 0; j < 8; ++j) o[j] = (short)f2bf(tile[orr + j][cc]);
    *(short8*)(out + eoff + (size_t)(c0 + cc) * R + r0 + orr) = o;
  }
}

// ---------------- router: logits, top-2, weights, expert bucketing ---------
__global__ void router_kernel(const float* __restrict__ x, const float* __restrict__ Wr,
                              const float* __restrict__ br,
                              int* __restrict__ cnt, int* __restrict__ tok_of,
                              int* __restrict__ k_of, float* __restrict__ tok_w) {
  int t = blockIdx.x * 4 + (threadIdx.x >> 6);
  int l = threadIdx.x & 63;
  const float* xr = x + (size_t)t * D_MODEL;
  float a[8] = {0.f,0.f,0.f,0.f,0.f,0.f,0.f,0.f};
  for (int d = l; d < D_MODEL; d += 64) {
    float xv = xr[d];
    const float4* w4 = (const float4*)(Wr + d * 8);
    float4 wa = w4[0], wb = w4[1];
    a[0] += xv * wa.x; a[1] += xv * wa.y; a[2] += xv * wa.z; a[3] += xv * wa.w;
    a[4] += xv * wb.x; a[5] += xv * wb.y; a[6] += xv * wb.z; a[7] += xv * wb.w;
  }
#pragma unroll
  for (int e = 0; e < 8; ++e) {
    float v = a[e];
#pragma unroll
    for (int off = 32; off > 0; off >>= 1) v += __shfl_xor(v, off);
    a[e] = v + br[e];
  }
  if (l == 0) {
    int i1 = 0; float v1 = a[0];
#pragma unroll
    for (int e = 1; e < 8; ++e) if (a[e] > v1) { v1 = a[e]; i1 = e; }
    int i2 = -1; float v2 = -1e30f;
#pragma unroll
    for (int e = 0; e < 8; ++e) if (e != i1 && a[e] > v2) { v2 = a[e]; i2 = e; }
    float e2 = __expf(v2 - v1);
    float inv = 1.0f / (1.0f + e2);
    int p1 = atomicAdd(cnt + i1, 1);
    tok_of[i1 * T_TOK + p1] = t; k_of[i1 * T_TOK + p1] = 0;
    int p2 = atomicAdd(cnt + i2, 1);
    tok_of[i2 * T_TOK + p2] = t; k_of[i2 * T_TOK + p2] = 1;
    tok_w[t * 2 + 0] = inv; tok_w[t * 2 + 1] = e2 * inv;
  }
}

// meta ints: [0]=ntiles, [1..9]=base[0..8] (padded prefix), [16..16+MAXT)=tile_e,
// [16+MAXT..16+2*MAXT)=tile_row0
__global__ void setup_kernel(const int* __restrict__ cnt, int* __restrict__ meta) {
  if (threadIdx.x != 0 || blockIdx.x != 0) return;
  int base = 0, nt = 0;
  meta[1] = 0;
  for (int e = 0; e < NE; ++e) {
    int c = cnt[e];
    int tiles = (c + BM - 1) / BM;
    for (int i = 0; i < tiles; ++i) {
      meta[16 + nt] = e;
      meta[16 + MAXT + nt] = base + i * BM;
      nt++;
    }
    base += tiles * BM;
    meta[2 + e] = base;
  }
  meta[0] = nt;
}

// ---------------- gather tokens into permuted bf16 buffer ------------------
__global__ void gather_kernel(const float* __restrict__ x, const int* __restrict__ cnt,
                              const int* __restrict__ meta, const int* __restrict__ tok_of,
                              const int* __restrict__ k_of, const float* __restrict__ tok_w,
                              uint16_t* __restrict__ xp,
                              int* __restrict__ row2tok, float* __restrict__ row2w) {
  int r = blockIdx.x * 4 + (threadIdx.x >> 6);
  int l = threadIdx.x & 63;
  int total = meta[9];
  if (r >= total) return;
  int e = 0;
#pragma unroll
  for (int i = 1; i < 8; ++i) if (r >= meta[1 + i]) e = i;
  int p = r - meta[1 + e];
  uint16_t* dst = xp + (size_t)r * D_MODEL + l * 16;
  if (p < cnt[e]) {
    int t = tok_of[e * T_TOK + p];
    if (l == 0) {
      row2tok[r] = t;
      row2w[r] = tok_w[t * 2 + k_of[e * T_TOK + p]];
    }
    const float4* src = (const float4*)(x + (size_t)t * D_MODEL + l * 16);
    short8 o0, o1;
    float4 v0 = src[0], v1 = src[1], v2 = src[2], v3 = src[3];
    o0[0] = (short)f2bf(v0.x); o0[1] = (short)f2bf(v0.y);
    o0[2] = (short)f2bf(v0.z); o0[3] = (short)f2bf(v0.w);
    o0[4] = (short)f2bf(v1.x); o0[5] = (short)f2bf(v1.y);
    o0[6] = (short)f2bf(v1.z); o0[7] = (short)f2bf(v1.w);
    o1[0] = (short)f2bf(v2.x); o1[1] = (short)f2bf(v2.y);
    o1[2] = (short)f2bf(v2.z); o1[3] = (short)f2bf(v2.w);
    o1[4] = (short)f2bf(v3.x); o1[5] = (short)f2bf(v3.y);
    o1[6] = (short)f2bf(v3.z); o1[7] = (short)f2bf(v3.w);
    *(short8*)dst = o0;
    *(short8*)(dst + 8) = o1;
  } else {
    if (l == 0) { row2tok[r] = -1; row2w[r] = 0.f; }
    short8 z = {0,0,0,0,0,0,0,0};
    *(short8*)dst = z;
    *(short8*)(dst + 8) = z;
  }
}

// ---------------- grouped GEMM: 256x256 tile, BK=32, 8 waves, 8-phase ------
// 512 thr = 8 waves (2M x 4N); per-wave out 128x64 (8 mf x 4 nf frags).
// Triple-buffered LDS (3 x 32KB): tile T in buf T%3; stages during T's phases
// write buf (T+2)%3 -> never a buffer under read (race-free 2-deep prefetch).
// Per K-tile: 2 phases x {ds_read frags; stage 2 gloads; barrier; lgkmcnt(0);
// setprio(1); 16 MFMA; setprio(0); barrier}; counted vmcnt(4) once per tile.
// Swizzle: k-seg s of row r stored at seg s^(r&3) (source-pre-swizzled for
// linear global_load_lds dests; reads apply same XOR) -> conflict-free b128.
template<int KD, int ND, int KSPLIT, bool FUSED_OUT>
__global__ __launch_bounds__(512, 2) void moe_gemm(
    const uint16_t* __restrict__ A, const uint16_t* __restrict__ Bt,
    const float* __restrict__ bias, uint16_t* __restrict__ Cb,
    float* __restrict__ out, const int* __restrict__ row2tok,
    const float* __restrict__ row2w, const int* __restrict__ meta) {
  constexpr int NTX = ND / BN;
  constexpr int KS  = KD / KSPLIT;
  constexpr int NT  = KS / 32;
  constexpr int NWG = NTX * MAXT;

  int bid = blockIdx.y * NTX + blockIdx.x;
  int bid2 = (bid & 7) * (NWG >> 3) + (bid >> 3);   // bijective XCD swizzle
  int mt = bid2 / NTX;
  int nt = meta[0];
  if (mt >= nt) return;
  int n0 = (bid2 % NTX) * BN;
  int e = meta[16 + mt];
  int row0 = meta[16 + MAXT + mt];
  int ks = blockIdx.z;

  __shared__ __align__(16) uint16_t L[49152];   // 96 KB: 3 bufs x (A 16K | B 16K)

  int tid = threadIdx.x;
  int l = tid & 63, w = tid >> 6;
  int wrow = w >> 2, wcol = w & 3;
  int swz = ((l >> 4) ^ (l & 3)) * 8;
  int arow_base = (wrow * 128 + (l & 15)) * 32 + swz;
  int brow_base = 8192 + (wcol * 64 + (l & 15)) * 32 + swz;

  int sr = tid >> 2;                              // stage row 0..127
  size_t s_src = (size_t)sr * KD + ((tid & 3) ^ (sr & 3)) * 8;
  int s_dst = tid * 8;

  const uint16_t* Ab = A + (size_t)row0 * KD + ks * KS;
  const uint16_t* Bb = Bt + ((size_t)e * ND + n0) * KD + ks * KS;

  f32x4 acc[8][4];
#pragma unroll
  for (int m = 0; m < 8; ++m)
#pragma unroll
    for (int n = 0; n < 4; ++n) acc[m][n] = (f32x4){0.f, 0.f, 0.f, 0.f};

  auto stageA = [&](int sb, int kt) {
    const uint16_t* ga = Ab + kt * 32;
    uint16_t* ld = L + sb * 16384;
    GLOAD16(ga + s_src, ld + s_dst);
    GLOAD16(ga + s_src + (size_t)128 * KD, ld + s_dst + 4096);
  };
  auto stageB = [&](int sb, int kt) {
    const uint16_t* gb = Bb + kt * 32;
    uint16_t* ld = L + sb * 16384 + 8192;
    GLOAD16(gb + s_src, ld + s_dst);
    GLOAD16(gb + s_src + (size_t)128 * KD, ld + s_dst + 4096);
  };

#define TILE(B0, DO_ST, SB, KT2, VM) do {                                        \
    const uint16_t* Lb = L + (B0) * 16384;                                       \
    short8 af[4], bfr[4];                                                        \
    _Pragma("unroll") for (int n = 0; n < 4; ++n)                                \
      bfr[n] = *(const short8*)(Lb + brow_base + n * 512);                       \
    _Pragma("unroll") for (int m = 0; m < 4; ++m)                                \
      af[m] = *(const short8*)(Lb + arow_base + m * 512);                        \
    if (DO_ST) stageA(SB, KT2);                                                  \
    __builtin_amdgcn_s_barrier();                                                \
    asm volatile("s_waitcnt lgkmcnt(0)" ::: "memory");                           \
    __builtin_amdgcn_sched_barrier(0);                                           \
    __builtin_amdgcn_s_setprio(1);                                               \
    _Pragma("unroll") for (int m = 0; m < 4; ++m)                                \
      _Pragma("unroll") for (int n = 0; n < 4; ++n)                              \
        acc[m][n] = __builtin_amdgcn_mfma_f32_16x16x32_bf16(af[m], bfr[n],       \
                                                            acc[m][n], 0, 0, 0); \
    __builtin_amdgcn_s_setprio(0);                                               \
    __builtin_amdgcn_s_barrier();                                                \
    _Pragma("unroll") for (int m = 0; m < 4; ++m)                                \
      af[m] = *(const short8*)(Lb + arow_base + 2048 + m * 512);                 \
    if (DO_ST) stageB(SB, KT2);                                                  \
    asm volatile("s_waitcnt vmcnt(" VM ")" ::: "memory");                        \
    __builtin_amdgcn_s_barrier();                                                \
    asm volatile("s_waitcnt lgkmcnt(0)" ::: "memory");                           \
    __builtin_amdgcn_sched_barrier(0);                                           \
    __builtin_amdgcn_s_setprio(1);                                               \
    _Pragma("unroll") for (int m = 0; m < 4; ++m)                                \
      _Pragma("unroll") for (int n = 0; n < 4; ++n)                              \
        acc[4 + m][n] = __builtin_amdgcn_mfma_f32_16x16x32_bf16(af[m], bfr[n],   \
                                                         acc[4 + m][n], 0, 0, 0);\
    __builtin_amdgcn_s_setprio(0);                                               \
    __builtin_amdgcn_s_barrier();                                                \
  } while (0)

  // prologue: stage tiles 0,1 -> bufs 0,1; wait tile0 (leave tile1's 4 in flight)
  stageA(0, 0); stageB(0, 0);
  stageA(1, 1); stageB(1, 1);
  asm volatile("s_waitcnt vmcnt(4)" ::: "memory");
  __builtin_amdgcn_s_barrier();

  int b0 = 0;
  for (int t = 0; t + 2 < NT; ++t) {
    int sb = b0 + 2; if (sb >= 3) sb -= 3;
    TILE(b0, 1, sb, t + 2, "4");
    b0 = (b0 == 2) ? 0 : b0 + 1;
  }
  TILE(b0, 0, 0, 0, "0");
  b0 = (b0 == 2) ? 0 : b0 + 1;
  TILE(b0, 0, 0, 0, "0");
#undef TILE

  // ---------------- epilogue ----------------
  if (!FUSED_OUT) {
#pragma unroll
    for (int mf = 0; mf < 8; ++mf) {
      int rbase = row0 + wrow * 128 + mf * 16 + (l >> 4) * 4;
#pragma unroll
      for (int n = 0; n < 4; ++n) {
        int col = n0 + wcol * 64 + n * 16 + (l & 15);
        float bv = bias[e * ND + col];
#pragma unroll
        for (int r = 0; r < 4; ++r)
          Cb[(size_t)(rbase + r) * ND + col] = f2bf(fmaxf(acc[mf][n][r] + bv, 0.f));
      }
    }
  } else {
    float bv[4];
#pragma unroll
    for (int n = 0; n < 4; ++n)
      bv[n] = (ks == 0) ? bias[e * ND + n0 + wcol * 64 + n * 16 + (l & 15)] : 0.f;
#pragma unroll
    for (int mf = 0; mf < 8; ++mf) {
#pragma unroll
      for (int r = 0; r < 4; ++r) {
        int grow = row0 + wrow * 128 + mf * 16 + (l >> 4) * 4 + r;
        int tok = row2tok[grow];
        float wgt = row2w[grow];
        if (tok >= 0) {
#pragma unroll
          for (int n = 0; n < 4; ++n) {
            int col = n0 + wcol * 64 + n * 16 + (l & 15);
            atomicAdd(out + (size_t)tok * ND + col, wgt * (acc[mf][n][r] + bv[n]));
          }
        }
      }
    }
  }
}

extern "C" void kernel_launch(void* const* d_in, const int* in_sizes, int n_in,
                              void* d_out, int out_size, void* d_ws, size_t ws_size,
                              hipStream_t stream) {
  const float* x  = (const float*)d_in[0];
  const float* Wr = (const float*)d_in[1];
  const float* br = (const float*)d_in[2];
  const float* W1 = (const float*)d_in[3];
  const float* b1 = (const float*)d_in[4];
  const float* W2 = (const float*)d_in[5];
  const float* b2 = (const float*)d_in[6];
  float* out = (float*)d_out;

  char* ws = (char*)d_ws;
  size_t off = 0;
  auto alloc = [&](size_t bytes) -> void* {
    void* p = ws + off;
    off += (bytes + 255) & ~(size_t)255;
    return p;
  };
  uint16_t* W1T    = (uint16_t*)alloc((size_t)NE * D_MODEL * D_HIDDEN * 2);
  uint16_t* W2T    = (uint16_t*)alloc((size_t)NE * D_MODEL * D_HIDDEN * 2);
  uint16_t* xp     = (uint16_t*)alloc((size_t)ROWS_CAP * D_MODEL * 2);
  uint16_t* hp     = (uint16_t*)alloc((size_t)ROWS_CAP * D_HIDDEN * 2);
  int*      cnt    = (int*)alloc(NE * 4);
  int*      tok_of = (int*)alloc((size_t)NE * T_TOK * 4);
  int*      k_of   = (int*)alloc((size_t)NE * T_TOK * 4);
  float*    tok_w  = (float*)alloc(T_TOK * 2 * 4);
  int*      row2tok= (int*)alloc(ROWS_CAP * 4);
  float*    row2w  = (float*)alloc(ROWS_CAP * 4);
  int*      meta   = (int*)alloc((16 + 2 * MAXT) * 4);

  if (ws_size < off) return;  // workspace too small: visible failure

  hipMemsetAsync(cnt, 0, NE * 4, stream);
  hipMemsetAsync(out, 0, (size_t)out_size * 4, stream);
  transpose_cvt<<<dim3(D_HIDDEN / 64, D_MODEL / 64, NE), 256, 0, stream>>>(
      W1, W1T, D_MODEL, D_HIDDEN);
  transpose_cvt<<<dim3(D_MODEL / 64, D_HIDDEN / 64, NE), 256, 0, stream>>>(
      W2, W2T, D_HIDDEN, D_MODEL);
  router_kernel<<<T_TOK / 4, 256, 0, stream>>>(x, Wr, br, cnt, tok_of, k_of, tok_w);
  setup_kernel<<<1, 64, 0, stream>>>(cnt, meta);
  gather_kernel<<<ROWS_CAP / 4, 256, 0, stream>>>(x, cnt, meta, tok_of, k_of, tok_w,
                                                  xp, row2tok, row2w);
  moe_gemm<D_MODEL, D_HIDDEN, 1, false><<<dim3(D_HIDDEN / BN, MAXT, 1), 512, 0, stream>>>(
      xp, W1T, b1, hp, nullptr, nullptr, nullptr, meta);
  moe_gemm<D_HIDDEN, D_MODEL, 2, true><<<dim3(D_MODEL / BN, MAXT, 2), 512, 0, stream>>>(
      hp, W2T, b2, nullptr, out, row2tok, row2w, meta);
}

// Round 5
// 759.008 us; speedup vs baseline: 1.0168x; 1.0168x over previous
//
#include <hip/hip_runtime.h>
#include <stdint.h>

#define D_MODEL  1024
#define D_HIDDEN 4096
#define NE       8
#define T_TOK    8192
#define BM       256
#define BN       256
#define MAXT     72
#define ROWS_CAP 18432

typedef __attribute__((ext_vector_type(8))) short short8;
typedef __attribute__((ext_vector_type(4))) float f32x4;

__device__ inline uint16_t f2bf(float f) {
  uint32_t u = __float_as_uint(f);
  uint32_t r = (u + 0x7fffu + ((u >> 16) & 1u)) >> 16;
  return (uint16_t)r;
}

#define GLOAD16(gp, lp) __builtin_amdgcn_global_load_lds( \
  (const __attribute__((address_space(1))) uint32_t*)(gp), \
  (__attribute__((address_space(3))) uint32_t*)(lp), 16, 0, 0)

// ---------------- transpose + f32->bf16 convert: in [R][C] -> out [C][R] ----
// 64x64 tile, 256 threads; coalesced f32x4 reads, coalesced 16B bf16 writes.
__global__ void transpose_cvt(const float* __restrict__ in, uint16_t* __restrict__ out,
                              int R, int C) {
  __shared__ float tile[64][65];
  size_t eoff = (size_t)blockIdx.z * R * C;
  int c0 = blockIdx.x * 64, r0 = blockIdx.y * 64;
  int t = threadIdx.x;
  int lr = t >> 4, lc4 = (t & 15) * 4;
#pragma unroll
  for (int i = 0; i < 4; ++i) {
    int rr = i * 16 + lr;
    float4 v = *(const float4*)(in + eoff + (size_t)(r0 + rr) * C + c0 + lc4);
    tile[rr][lc4] = v.x; tile[rr][lc4 + 1] = v.y;
    tile[rr][lc4 + 2] = v.z; tile[rr][lc4 + 3] = v.w;
  }
  __syncthreads();
  int oc = t >> 3, orr = (t & 7) * 8;
#pragma unroll
  for (int i = 0; i < 2; ++i) {
    int cc = i * 32 + oc;
    short8 o;
#pragma unroll
    for (int j = 0; j < 8; ++j) o[j] = (short)f2bf(tile[orr + j][cc]);
    *(short8*)(out + eoff + (size_t)(c0 + cc) * R + r0 + orr) = o;
  }
}

// ---------------- router: logits, top-2, weights, expert bucketing ---------
__global__ void router_kernel(const float* __restrict__ x, const float* __restrict__ Wr,
                              const float* __restrict__ br,
                              int* __restrict__ cnt, int* __restrict__ tok_of,
                              int* __restrict__ k_of, float* __restrict__ tok_w) {
  int t = blockIdx.x * 4 + (threadIdx.x >> 6);
  int l = threadIdx.x & 63;
  const float* xr = x + (size_t)t * D_MODEL;
  float a[8] = {0.f,0.f,0.f,0.f,0.f,0.f,0.f,0.f};
  for (int d = l; d < D_MODEL; d += 64) {
    float xv = xr[d];
    const float4* w4 = (const float4*)(Wr + d * 8);
    float4 wa = w4[0], wb = w4[1];
    a[0] += xv * wa.x; a[1] += xv * wa.y; a[2] += xv * wa.z; a[3] += xv * wa.w;
    a[4] += xv * wb.x; a[5] += xv * wb.y; a[6] += xv * wb.z; a[7] += xv * wb.w;
  }
#pragma unroll
  for (int e = 0; e < 8; ++e) {
    float v = a[e];
#pragma unroll
    for (int off = 32; off > 0; off >>= 1) v += __shfl_xor(v, off);
    a[e] = v + br[e];
  }
  if (l == 0) {
    int i1 = 0; float v1 = a[0];
#pragma unroll
    for (int e = 1; e < 8; ++e) if (a[e] > v1) { v1 = a[e]; i1 = e; }
    int i2 = -1; float v2 = -1e30f;
#pragma unroll
    for (int e = 0; e < 8; ++e) if (e != i1 && a[e] > v2) { v2 = a[e]; i2 = e; }
    float e2 = __expf(v2 - v1);
    float inv = 1.0f / (1.0f + e2);
    int p1 = atomicAdd(cnt + i1, 1);
    tok_of[i1 * T_TOK + p1] = t; k_of[i1 * T_TOK + p1] = 0;
    int p2 = atomicAdd(cnt + i2, 1);
    tok_of[i2 * T_TOK + p2] = t; k_of[i2 * T_TOK + p2] = 1;
    tok_w[t * 2 + 0] = inv; tok_w[t * 2 + 1] = e2 * inv;
  }
}

// meta ints: [0]=ntiles, [1..9]=base[0..8] (padded prefix), [16..16+MAXT)=tile_e,
// [16+MAXT..16+2*MAXT)=tile_row0
__global__ void setup_kernel(const int* __restrict__ cnt, int* __restrict__ meta) {
  if (threadIdx.x != 0 || blockIdx.x != 0) return;
  int base = 0, nt = 0;
  meta[1] = 0;
  for (int e = 0; e < NE; ++e) {
    int c = cnt[e];
    int tiles = (c + BM - 1) / BM;
    for (int i = 0; i < tiles; ++i) {
      meta[16 + nt] = e;
      meta[16 + MAXT + nt] = base + i * BM;
      nt++;
    }
    base += tiles * BM;
    meta[2 + e] = base;
  }
  meta[0] = nt;
}

// ---------------- gather tokens into permuted bf16 buffer ------------------
__global__ void gather_kernel(const float* __restrict__ x, const int* __restrict__ cnt,
                              const int* __restrict__ meta, const int* __restrict__ tok_of,
                              const int* __restrict__ k_of, const float* __restrict__ tok_w,
                              uint16_t* __restrict__ xp,
                              int* __restrict__ row2tok, float* __restrict__ row2w) {
  int r = blockIdx.x * 4 + (threadIdx.x >> 6);
  int l = threadIdx.x & 63;
  int total = meta[9];
  if (r >= total) return;
  int e = 0;
#pragma unroll
  for (int i = 1; i < 8; ++i) if (r >= meta[1 + i]) e = i;
  int p = r - meta[1 + e];
  uint16_t* dst = xp + (size_t)r * D_MODEL + l * 16;
  if (p < cnt[e]) {
    int t = tok_of[e * T_TOK + p];
    if (l == 0) {
      row2tok[r] = t;
      row2w[r] = tok_w[t * 2 + k_of[e * T_TOK + p]];
    }
    const float4* src = (const float4*)(x + (size_t)t * D_MODEL + l * 16);
    short8 o0, o1;
    float4 v0 = src[0], v1 = src[1], v2 = src[2], v3 = src[3];
    o0[0] = (short)f2bf(v0.x); o0[1] = (short)f2bf(v0.y);
    o0[2] = (short)f2bf(v0.z); o0[3] = (short)f2bf(v0.w);
    o0[4] = (short)f2bf(v1.x); o0[5] = (short)f2bf(v1.y);
    o0[6] = (short)f2bf(v1.z); o0[7] = (short)f2bf(v1.w);
    o1[0] = (short)f2bf(v2.x); o1[1] = (short)f2bf(v2.y);
    o1[2] = (short)f2bf(v2.z); o1[3] = (short)f2bf(v2.w);
    o1[4] = (short)f2bf(v3.x); o1[5] = (short)f2bf(v3.y);
    o1[6] = (short)f2bf(v3.z); o1[7] = (short)f2bf(v3.w);
    *(short8*)dst = o0;
    *(short8*)(dst + 8) = o1;
  } else {
    if (l == 0) { row2tok[r] = -1; row2w[r] = 0.f; }
    short8 z = {0,0,0,0,0,0,0,0};
    *(short8*)dst = z;
    *(short8*)(dst + 8) = z;
  }
}

// ---------------- grouped GEMM: 256x256 tile, BK=32, 8 waves, phase-split --
// 512 thr = 8 waves (2M x 4N); per-wave out 128x64 (8 mf x 4 nf frags).
// Triple-buffered LDS (3 x 32KB): tile T in buf T%3; stages during T's phases
// write buf (T+2)%3 -> never a buffer under read (race-free 2-deep prefetch).
// Counted vmcnt(4) once per K-tile (T4); setprio around MFMA (T5).
// Swizzle (T2, rule #21): 64B rows, 4 segs; seg s of row r stored at slot
// s^((r>>1)&3) -- row base banks alternate 0/16 with period 2, so XOR of
// (r>>1)&3 gives exactly 2 rows per b128 slot = free (m136). Source-side
// pre-swizzle (linear gload_lds dest) + identical XOR on reads.
template<int KD, int ND, int KSPLIT, bool FUSED_OUT>
__global__ __launch_bounds__(512, 2) void moe_gemm(
    const uint16_t* __restrict__ A, const uint16_t* __restrict__ Bt,
    const float* __restrict__ bias, uint16_t* __restrict__ Cb,
    float* __restrict__ out, const int* __restrict__ row2tok,
    const float* __restrict__ row2w, const int* __restrict__ meta) {
  constexpr int NTX = ND / BN;
  constexpr int KS  = KD / KSPLIT;
  constexpr int NT  = KS / 32;
  constexpr int NWG = NTX * MAXT;

  int bid = blockIdx.y * NTX + blockIdx.x;
  int bid2 = (bid & 7) * (NWG >> 3) + (bid >> 3);   // bijective XCD swizzle
  int mt = bid2 / NTX;
  int nt = meta[0];
  if (mt >= nt) return;
  int n0 = (bid2 % NTX) * BN;
  int e = meta[16 + mt];
  int row0 = meta[16 + MAXT + mt];
  int ks = blockIdx.z;

  __shared__ __align__(16) uint16_t L[49152];   // 96 KB: 3 bufs x (A 16K | B 16K)

  int tid = threadIdx.x;
  int l = tid & 63, w = tid >> 6;
  int wrow = w >> 2, wcol = w & 3;
  int swz = ((l >> 4) ^ (((l & 15) >> 1) & 3)) * 8;   // FIX: (row>>1)&3, not row&3
  int arow_base = (wrow * 128 + (l & 15)) * 32 + swz;
  int brow_base = 8192 + (wcol * 64 + (l & 15)) * 32 + swz;

  int sr = tid >> 2;                              // stage row 0..127
  size_t s_src = (size_t)sr * KD + ((tid & 3) ^ ((sr >> 1) & 3)) * 8;  // FIX
  int s_dst = tid * 8;

  const uint16_t* Ab = A + (size_t)row0 * KD + ks * KS;
  const uint16_t* Bb = Bt + ((size_t)e * ND + n0) * KD + ks * KS;

  f32x4 acc[8][4];
#pragma unroll
  for (int m = 0; m < 8; ++m)
#pragma unroll
    for (int n = 0; n < 4; ++n) acc[m][n] = (f32x4){0.f, 0.f, 0.f, 0.f};

  auto stageA = [&](int sb, int kt) {
    const uint16_t* ga = Ab + kt * 32;
    uint16_t* ld = L + sb * 16384;
    GLOAD16(ga + s_src, ld + s_dst);
    GLOAD16(ga + s_src + (size_t)128 * KD, ld + s_dst + 4096);
  };
  auto stageB = [&](int sb, int kt) {
    const uint16_t* gb = Bb + kt * 32;
    uint16_t* ld = L + sb * 16384 + 8192;
    GLOAD16(gb + s_src, ld + s_dst);
    GLOAD16(gb + s_src + (size_t)128 * KD, ld + s_dst + 4096);
  };

#define TILE(B0, DO_ST, SB, KT2, VM) do {                                        \
    const uint16_t* Lb = L + (B0) * 16384;                                       \
    short8 af[4], bfr[4];                                                        \
    _Pragma("unroll") for (int n = 0; n < 4; ++n)                                \
      bfr[n] = *(const short8*)(Lb + brow_base + n * 512);                       \
    _Pragma("unroll") for (int m = 0; m < 4; ++m)                                \
      af[m] = *(const short8*)(Lb + arow_base + m * 512);                        \
    if (DO_ST) stageA(SB, KT2);                                                  \
    __builtin_amdgcn_s_barrier();                                                \
    asm volatile("s_waitcnt lgkmcnt(0)" ::: "memory");                           \
    __builtin_amdgcn_sched_barrier(0);                                           \
    __builtin_amdgcn_s_setprio(1);                                               \
    _Pragma("unroll") for (int m = 0; m < 4; ++m)                                \
      _Pragma("unroll") for (int n = 0; n < 4; ++n)                              \
        acc[m][n] = __builtin_amdgcn_mfma_f32_16x16x32_bf16(af[m], bfr[n],       \
                                                            acc[m][n], 0, 0, 0); \
    __builtin_amdgcn_s_setprio(0);                                               \
    __builtin_amdgcn_s_barrier();                                                \
    _Pragma("unroll") for (int m = 0; m < 4; ++m)                                \
      af[m] = *(const short8*)(Lb + arow_base + 2048 + m * 512);                 \
    if (DO_ST) stageB(SB, KT2);                                                  \
    asm volatile("s_waitcnt vmcnt(" VM ")" ::: "memory");                        \
    __builtin_amdgcn_s_barrier();                                                \
    asm volatile("s_waitcnt lgkmcnt(0)" ::: "memory");                           \
    __builtin_amdgcn_sched_barrier(0);                                           \
    __builtin_amdgcn_s_setprio(1);                                               \
    _Pragma("unroll") for (int m = 0; m < 4; ++m)                                \
      _Pragma("unroll") for (int n = 0; n < 4; ++n)                              \
        acc[4 + m][n] = __builtin_amdgcn_mfma_f32_16x16x32_bf16(af[m], bfr[n],   \
                                                         acc[4 + m][n], 0, 0, 0);\
    __builtin_amdgcn_s_setprio(0);                                               \
    __builtin_amdgcn_s_barrier();                                                \
  } while (0)

  // prologue: stage tiles 0,1 -> bufs 0,1; wait tile0 (leave tile1's 4 in flight)
  stageA(0, 0); stageB(0, 0);
  stageA(1, 1); stageB(1, 1);
  asm volatile("s_waitcnt vmcnt(4)" ::: "memory");
  __builtin_amdgcn_s_barrier();

  int b0 = 0;
  for (int t = 0; t + 2 < NT; ++t) {
    int sb = b0 + 2; if (sb >= 3) sb -= 3;
    TILE(b0, 1, sb, t + 2, "4");
    b0 = (b0 == 2) ? 0 : b0 + 1;
  }
  TILE(b0, 0, 0, 0, "0");
  b0 = (b0 == 2) ? 0 : b0 + 1;
  TILE(b0, 0, 0, 0, "0");
#undef TILE

  // ---------------- epilogue ----------------
  if (!FUSED_OUT) {
#pragma unroll
    for (int mf = 0; mf < 8; ++mf) {
      int rbase = row0 + wrow * 128 + mf * 16 + (l >> 4) * 4;
#pragma unroll
      for (int n = 0; n < 4; ++n) {
        int col = n0 + wcol * 64 + n * 16 + (l & 15);
        float bv = bias[e * ND + col];
#pragma unroll
        for (int r = 0; r < 4; ++r)
          Cb[(size_t)(rbase + r) * ND + col] = f2bf(fmaxf(acc[mf][n][r] + bv, 0.f));
      }
    }
  } else {
    float bv[4];
#pragma unroll
    for (int n = 0; n < 4; ++n)
      bv[n] = (ks == 0) ? bias[e * ND + n0 + wcol * 64 + n * 16 + (l & 15)] : 0.f;
#pragma unroll
    for (int mf = 0; mf < 8; ++mf) {
#pragma unroll
      for (int r = 0; r < 4; ++r) {
        int grow = row0 + wrow * 128 + mf * 16 + (l >> 4) * 4 + r;
        int tok = row2tok[grow];
        float wgt = row2w[grow];
        if (tok >= 0) {
#pragma unroll
          for (int n = 0; n < 4; ++n) {
            int col = n0 + wcol * 64 + n * 16 + (l & 15);
            atomicAdd(out + (size_t)tok * ND + col, wgt * (acc[mf][n][r] + bv[n]));
          }
        }
      }
    }
  }
}

extern "C" void kernel_launch(void* const* d_in, const int* in_sizes, int n_in,
                              void* d_out, int out_size, void* d_ws, size_t ws_size,
                              hipStream_t stream) {
  const float* x  = (const float*)d_in[0];
  const float* Wr = (const float*)d_in[1];
  const float* br = (const float*)d_in[2];
  const float* W1 = (const float*)d_in[3];
  const float* b1 = (const float*)d_in[4];
  const float* W2 = (const float*)d_in[5];
  const float* b2 = (const float*)d_in[6];
  float* out = (float*)d_out;

  char* ws = (char*)d_ws;
  size_t off = 0;
  auto alloc = [&](size_t bytes) -> void* {
    void* p = ws + off;
    off += (bytes + 255) & ~(size_t)255;
    return p;
  };
  uint16_t* W1T    = (uint16_t*)alloc((size_t)NE * D_MODEL * D_HIDDEN * 2);
  uint16_t* W2T    = (uint16_t*)alloc((size_t)NE * D_MODEL * D_HIDDEN * 2);
  uint16_t* xp     = (uint16_t*)alloc((size_t)ROWS_CAP * D_MODEL * 2);
  uint16_t* hp     = (uint16_t*)alloc((size_t)ROWS_CAP * D_HIDDEN * 2);
  int*      cnt    = (int*)alloc(NE * 4);
  int*      tok_of = (int*)alloc((size_t)NE * T_TOK * 4);
  int*      k_of   = (int*)alloc((size_t)NE * T_TOK * 4);
  float*    tok_w  = (float*)alloc(T_TOK * 2 * 4);
  int*      row2tok= (int*)alloc(ROWS_CAP * 4);
  float*    row2w  = (float*)alloc(ROWS_CAP * 4);
  int*      meta   = (int*)alloc((16 + 2 * MAXT) * 4);

  if (ws_size < off) return;  // workspace too small: visible failure

  hipMemsetAsync(cnt, 0, NE * 4, stream);
  hipMemsetAsync(out, 0, (size_t)out_size * 4, stream);
  transpose_cvt<<<dim3(D_HIDDEN / 64, D_MODEL / 64, NE), 256, 0, stream>>>(
      W1, W1T, D_MODEL, D_HIDDEN);
  transpose_cvt<<<dim3(D_MODEL / 64, D_HIDDEN / 64, NE), 256, 0, stream>>>(
      W2, W2T, D_HIDDEN, D_MODEL);
  router_kernel<<<T_TOK / 4, 256, 0, stream>>>(x, Wr, br, cnt, tok_of, k_of, tok_w);
  setup_kernel<<<1, 64, 0, stream>>>(cnt, meta);
  gather_kernel<<<ROWS_CAP / 4, 256, 0, stream>>>(x, cnt, meta, tok_of, k_of, tok_w,
                                                  xp, row2tok, row2w);
  moe_gemm<D_MODEL, D_HIDDEN, 1, false><<<dim3(D_HIDDEN / BN, MAXT, 1), 512, 0, stream>>>(
      xp, W1T, b1, hp, nullptr, nullptr, nullptr, meta);
  moe_gemm<D_HIDDEN, D_MODEL, 2, true><<<dim3(D_MODEL / BN, MAXT, 2), 512, 0, stream>>>(
      hp, W2T, b2, nullptr, out, row2tok, row2w, meta);
}

// Round 6
// 683.829 us; speedup vs baseline: 1.1286x; 1.1099x over previous
//
#include <hip/hip_runtime.h>
#include <stdint.h>

#define D_MODEL  1024
#define D_HIDDEN 4096
#define NE       8
#define T_TOK    8192
#define BM       128
#define BN       128
#define BK       64
#define MAXT     136
#define ROWS_CAP 17408

typedef __attribute__((ext_vector_type(8))) short short8;
typedef __attribute__((ext_vector_type(4))) float f32x4;

__device__ inline uint16_t f2bf(float f) {
  uint32_t u = __float_as_uint(f);
  uint32_t r = (u + 0x7fffu + ((u >> 16) & 1u)) >> 16;
  return (uint16_t)r;
}

#define GLOAD16(gp, lp) __builtin_amdgcn_global_load_lds( \
  (const __attribute__((address_space(1))) uint32_t*)(gp), \
  (__attribute__((address_space(3))) uint32_t*)(lp), 16, 0, 0)

// ---------------- transpose + f32->bf16 convert: in [R][C] -> out [C][R] ----
// 64x64 tile, 256 threads; coalesced f32x4 reads, coalesced 16B bf16 writes.
__global__ void transpose_cvt(const float* __restrict__ in, uint16_t* __restrict__ out,
                              int R, int C) {
  __shared__ float tile[64][65];
  size_t eoff = (size_t)blockIdx.z * R * C;
  int c0 = blockIdx.x * 64, r0 = blockIdx.y * 64;
  int t = threadIdx.x;
  int lr = t >> 4, lc4 = (t & 15) * 4;
#pragma unroll
  for (int i = 0; i < 4; ++i) {
    int rr = i * 16 + lr;
    float4 v = *(const float4*)(in + eoff + (size_t)(r0 + rr) * C + c0 + lc4);
    tile[rr][lc4] = v.x; tile[rr][lc4 + 1] = v.y;
    tile[rr][lc4 + 2] = v.z; tile[rr][lc4 + 3] = v.w;
  }
  __syncthreads();
  int oc = t >> 3, orr = (t & 7) * 8;
#pragma unroll
  for (int i = 0; i < 2; ++i) {
    int cc = i * 32 + oc;
    short8 o;
#pragma unroll
    for (int j = 0; j < 8; ++j) o[j] = (short)f2bf(tile[orr + j][cc]);
    *(short8*)(out + eoff + (size_t)(c0 + cc) * R + r0 + orr) = o;
  }
}

// ---------------- router: logits, top-2, weights, expert bucketing ---------
__global__ void router_kernel(const float* __restrict__ x, const float* __restrict__ Wr,
                              const float* __restrict__ br,
                              int* __restrict__ cnt, int* __restrict__ tok_of,
                              int* __restrict__ k_of, float* __restrict__ tok_w) {
  int t = blockIdx.x * 4 + (threadIdx.x >> 6);
  int l = threadIdx.x & 63;
  const float* xr = x + (size_t)t * D_MODEL;
  float a[8] = {0.f,0.f,0.f,0.f,0.f,0.f,0.f,0.f};
  for (int d = l; d < D_MODEL; d += 64) {
    float xv = xr[d];
    const float4* w4 = (const float4*)(Wr + d * 8);
    float4 wa = w4[0], wb = w4[1];
    a[0] += xv * wa.x; a[1] += xv * wa.y; a[2] += xv * wa.z; a[3] += xv * wa.w;
    a[4] += xv * wb.x; a[5] += xv * wb.y; a[6] += xv * wb.z; a[7] += xv * wb.w;
  }
#pragma unroll
  for (int e = 0; e < 8; ++e) {
    float v = a[e];
#pragma unroll
    for (int off = 32; off > 0; off >>= 1) v += __shfl_xor(v, off);
    a[e] = v + br[e];
  }
  if (l == 0) {
    int i1 = 0; float v1 = a[0];
#pragma unroll
    for (int e = 1; e < 8; ++e) if (a[e] > v1) { v1 = a[e]; i1 = e; }
    int i2 = -1; float v2 = -1e30f;
#pragma unroll
    for (int e = 0; e < 8; ++e) if (e != i1 && a[e] > v2) { v2 = a[e]; i2 = e; }
    float e2 = __expf(v2 - v1);
    float inv = 1.0f / (1.0f + e2);
    int p1 = atomicAdd(cnt + i1, 1);
    tok_of[i1 * T_TOK + p1] = t; k_of[i1 * T_TOK + p1] = 0;
    int p2 = atomicAdd(cnt + i2, 1);
    tok_of[i2 * T_TOK + p2] = t; k_of[i2 * T_TOK + p2] = 1;
    tok_w[t * 2 + 0] = inv; tok_w[t * 2 + 1] = e2 * inv;
  }
}

// meta ints: [0]=ntiles, [1..9]=base[0..8] (padded prefix), [16..16+MAXT)=tile_e,
// [16+MAXT..16+2*MAXT)=tile_row0.  Single wave, register-resident scan.
__global__ void setup_kernel(const int* __restrict__ cnt, int* __restrict__ meta) {
  int l = threadIdx.x;
  int tiles[8], base[9], tpre[9];
  base[0] = 0; tpre[0] = 0;
#pragma unroll
  for (int e = 0; e < 8; ++e) {
    int c = cnt[e];
    tiles[e] = (c + BM - 1) / BM;
    base[e + 1] = base[e] + tiles[e] * BM;
    tpre[e + 1] = tpre[e] + tiles[e];
  }
  int nt = tpre[8];
  if (l == 0) meta[0] = nt;
  if (l < 9) meta[1 + l] = base[l];
  for (int i = l; i < nt; i += 64) {
    int e = 0;
#pragma unroll
    for (int k = 1; k < 8; ++k) if (i >= tpre[k]) e = k;
    meta[16 + i] = e;
    meta[16 + MAXT + i] = base[e] + (i - tpre[e]) * BM;
  }
}

// ---------------- gather tokens into permuted bf16 buffer ------------------
__global__ void gather_kernel(const float* __restrict__ x, const int* __restrict__ cnt,
                              const int* __restrict__ meta, const int* __restrict__ tok_of,
                              const int* __restrict__ k_of, const float* __restrict__ tok_w,
                              uint16_t* __restrict__ xp,
                              int* __restrict__ row2tok, float* __restrict__ row2w) {
  int r = blockIdx.x * 4 + (threadIdx.x >> 6);
  int l = threadIdx.x & 63;
  int total = meta[9];
  if (r >= total) return;
  int e = 0;
#pragma unroll
  for (int i = 1; i < 8; ++i) if (r >= meta[1 + i]) e = i;
  int p = r - meta[1 + e];
  uint16_t* dst = xp + (size_t)r * D_MODEL + l * 16;
  if (p < cnt[e]) {
    int t = tok_of[e * T_TOK + p];
    if (l == 0) {
      row2tok[r] = t;
      row2w[r] = tok_w[t * 2 + k_of[e * T_TOK + p]];
    }
    const float4* src = (const float4*)(x + (size_t)t * D_MODEL + l * 16);
    short8 o0, o1;
    float4 v0 = src[0], v1 = src[1], v2 = src[2], v3 = src[3];
    o0[0] = (short)f2bf(v0.x); o0[1] = (short)f2bf(v0.y);
    o0[2] = (short)f2bf(v0.z); o0[3] = (short)f2bf(v0.w);
    o0[4] = (short)f2bf(v1.x); o0[5] = (short)f2bf(v1.y);
    o0[6] = (short)f2bf(v1.z); o0[7] = (short)f2bf(v1.w);
    o1[0] = (short)f2bf(v2.x); o1[1] = (short)f2bf(v2.y);
    o1[2] = (short)f2bf(v2.z); o1[3] = (short)f2bf(v2.w);
    o1[4] = (short)f2bf(v3.x); o1[5] = (short)f2bf(v3.y);
    o1[6] = (short)f2bf(v3.z); o1[7] = (short)f2bf(v3.w);
    *(short8*)dst = o0;
    *(short8*)(dst + 8) = o1;
  } else {
    if (l == 0) { row2tok[r] = -1; row2w[r] = 0.f; }
    short8 z = {0,0,0,0,0,0,0,0};
    *(short8*)dst = z;
    *(short8*)(dst + 8) = z;
  }
}

// ---------------- grouped GEMM, 128x128 tile, BK=64, 16x16x32 bf16 MFMA ----
// Round-2 verified core (215 us, 0 bank conflicts, occ ~31%): single LDS
// buffer, global_load_lds width-16 staging, vmcnt(0)+syncthreads per K-step.
// Swizzle: element col in LDS slot (col ^ ((row&7)<<3)), source-pre-swizzled
// (rule #21); reads apply same XOR -> 2-way max (free, m136).
template<int KD, int ND, bool FUSED_OUT>
__global__ void moe_gemm(const uint16_t* __restrict__ A, const uint16_t* __restrict__ Bt,
                         const float* __restrict__ bias,
                         uint16_t* __restrict__ Cb, float* __restrict__ out,
                         const int* __restrict__ row2tok, const float* __restrict__ row2w,
                         const int* __restrict__ meta) {
  int nt = meta[0];
  int mt = blockIdx.y;
  if (mt >= nt) return;
  int e = meta[16 + mt];
  int row0 = meta[16 + MAXT + mt];
  int n0 = blockIdx.x * BN;

  __shared__ __align__(16) uint16_t lA[BM * BK];
  __shared__ __align__(16) uint16_t lB[BN * BK];

  int t = threadIdx.x;
  int w = t >> 6, l = t & 63;
  int wr = (w >> 1) * 64, wc = (w & 1) * 64;

  const uint16_t* Ab = A + (size_t)row0 * KD;
  const uint16_t* Bb = Bt + ((size_t)e * ND + n0) * KD;

  f32x4 acc[4][4];
#pragma unroll
  for (int m = 0; m < 4; ++m)
#pragma unroll
    for (int n = 0; n < 4; ++n) acc[m][n] = (f32x4){0.f, 0.f, 0.f, 0.f};

  int trow = t >> 3;                        // 0..31 (local row within 32-row chunk)
  int tcol = (t & 7) * 8;                   // linear LDS k-element offset
  int scol = tcol ^ ((trow & 7) << 3);      // swizzled global k-element offset

  for (int kt = 0; kt < KD / BK; ++kt) {
    int k0 = kt * BK;
    __syncthreads();
#pragma unroll
    for (int i = 0; i < 4; ++i) {
      GLOAD16(Ab + (size_t)(i * 32 + trow) * KD + k0 + scol, lA + (i * 32 + trow) * BK + tcol);
      GLOAD16(Bb + (size_t)(i * 32 + trow) * KD + k0 + scol, lB + (i * 32 + trow) * BK + tcol);
    }
    asm volatile("s_waitcnt vmcnt(0)" ::: "memory");
    __syncthreads();
#pragma unroll
    for (int kk = 0; kk < 2; ++kk) {
      short8 af[4], bf[4];
      int ko = kk * 32 + (l >> 4) * 8;
      int sw = ((l & 7) << 3);              // (row&7)<<3 for row = base + (l&15)
#pragma unroll
      for (int m = 0; m < 4; ++m)
        af[m] = *(const short8*)(lA + (wr + m * 16 + (l & 15)) * BK + (ko ^ sw));
#pragma unroll
      for (int n = 0; n < 4; ++n)
        bf[n] = *(const short8*)(lB + (wc + n * 16 + (l & 15)) * BK + (ko ^ sw));
#pragma unroll
      for (int m = 0; m < 4; ++m)
#pragma unroll
        for (int n = 0; n < 4; ++n)
          acc[m][n] = __builtin_amdgcn_mfma_f32_16x16x32_bf16(af[m], bf[n], acc[m][n], 0, 0, 0);
    }
  }

  // ---------------- epilogue ----------------
  if (!FUSED_OUT) {
#pragma unroll
    for (int m = 0; m < 4; ++m) {
      int row_b = row0 + wr + m * 16 + (l >> 4) * 4;
#pragma unroll
      for (int n = 0; n < 4; ++n) {
        int col = n0 + wc + n * 16 + (l & 15);
        float bv = bias[e * ND + col];
#pragma unroll
        for (int r = 0; r < 4; ++r)
          Cb[(size_t)(row_b + r) * ND + col] = f2bf(fmaxf(acc[m][n][r] + bv, 0.f));
      }
    }
  } else {
    float bv[4];
#pragma unroll
    for (int n = 0; n < 4; ++n)
      bv[n] = bias[e * ND + n0 + wc + n * 16 + (l & 15)];
#pragma unroll
    for (int m = 0; m < 4; ++m) {
#pragma unroll
      for (int r = 0; r < 4; ++r) {
        int grow = row0 + wr + m * 16 + (l >> 4) * 4 + r;
        int tok = row2tok[grow];
        float wgt = row2w[grow];
        if (tok >= 0) {
#pragma unroll
          for (int n = 0; n < 4; ++n) {
            int col = n0 + wc + n * 16 + (l & 15);
            atomicAdd(out + (size_t)tok * ND + col, wgt * (acc[m][n][r] + bv[n]));
          }
        }
      }
    }
  }
}

extern "C" void kernel_launch(void* const* d_in, const int* in_sizes, int n_in,
                              void* d_out, int out_size, void* d_ws, size_t ws_size,
                              hipStream_t stream) {
  const float* x  = (const float*)d_in[0];
  const float* Wr = (const float*)d_in[1];
  const float* br = (const float*)d_in[2];
  const float* W1 = (const float*)d_in[3];
  const float* b1 = (const float*)d_in[4];
  const float* W2 = (const float*)d_in[5];
  const float* b2 = (const float*)d_in[6];
  float* out = (float*)d_out;

  char* ws = (char*)d_ws;
  size_t off = 0;
  auto alloc = [&](size_t bytes) -> void* {
    void* p = ws + off;
    off += (bytes + 255) & ~(size_t)255;
    return p;
  };
  uint16_t* W1T    = (uint16_t*)alloc((size_t)NE * D_MODEL * D_HIDDEN * 2);
  uint16_t* W2T    = (uint16_t*)alloc((size_t)NE * D_MODEL * D_HIDDEN * 2);
  uint16_t* xp     = (uint16_t*)alloc((size_t)ROWS_CAP * D_MODEL * 2);
  uint16_t* hp     = (uint16_t*)alloc((size_t)ROWS_CAP * D_HIDDEN * 2);
  int*      cnt    = (int*)alloc(NE * 4);
  int*      tok_of = (int*)alloc((size_t)NE * T_TOK * 4);
  int*      k_of   = (int*)alloc((size_t)NE * T_TOK * 4);
  float*    tok_w  = (float*)alloc(T_TOK * 2 * 4);
  int*      row2tok= (int*)alloc(ROWS_CAP * 4);
  float*    row2w  = (float*)alloc(ROWS_CAP * 4);
  int*      meta   = (int*)alloc((16 + 2 * MAXT) * 4);

  if (ws_size < off) return;  // workspace too small: visible failure

  hipMemsetAsync(cnt, 0, NE * 4, stream);
  hipMemsetAsync(out, 0, (size_t)out_size * 4, stream);
  transpose_cvt<<<dim3(D_HIDDEN / 64, D_MODEL / 64, NE), 256, 0, stream>>>(
      W1, W1T, D_MODEL, D_HIDDEN);
  transpose_cvt<<<dim3(D_MODEL / 64, D_HIDDEN / 64, NE), 256, 0, stream>>>(
      W2, W2T, D_HIDDEN, D_MODEL);
  router_kernel<<<T_TOK / 4, 256, 0, stream>>>(x, Wr, br, cnt, tok_of, k_of, tok_w);
  setup_kernel<<<1, 64, 0, stream>>>(cnt, meta);
  gather_kernel<<<ROWS_CAP / 4, 256, 0, stream>>>(x, cnt, meta, tok_of, k_of, tok_w,
                                                  xp, row2tok, row2w);
  moe_gemm<D_MODEL, D_HIDDEN, false><<<dim3(D_HIDDEN / BN, MAXT), 256, 0, stream>>>(
      xp, W1T, b1, hp, nullptr, nullptr, nullptr, meta);
  moe_gemm<D_HIDDEN, D_MODEL, true><<<dim3(D_MODEL / BN, MAXT), 256, 0, stream>>>(
      hp, W2T, b2, nullptr, out, row2tok, row2w, meta);
}